// Round 5
// baseline (41191.971 us; speedup 1.0000x reference)
//
#include <hip/hip_runtime.h>
#include <math.h>

#define DT 0.01f
constexpr int T = 512, B = 128, I = 256, H = 1024, O = 256;
constexpr int K = I + H;          // 1280
constexpr int NKS_H = K / 32;     // 40 (W_h: ks 0..7 = x part, 8..39 = hu part)
constexpr int NKS_O = H / 32;     // 32 (W_o)

// ---- workspace layout (float offsets) ----
constexpr size_t OFF_OSUM  = 0;                              // B*H
constexpr size_t OFF_HUH0  = OFF_OSUM + (size_t)B * H;       // bf16 hi, B*H shorts
constexpr size_t OFF_HUL0  = OFF_HUH0 + (size_t)B * H / 2;
constexpr size_t OFF_HUH1  = OFF_HUL0 + (size_t)B * H / 2;
constexpr size_t OFF_HUL1  = OFF_HUH1 + (size_t)B * H / 2;
constexpr size_t OFF_COEF  = OFF_HUL1 + (size_t)B * H / 2;   // k1,k2,k3,al,1-al
constexpr size_t OFF_FLAGS = OFF_COEF + 5 * (size_t)H;       // 256 slots * 16 ints
constexpr size_t OFF_WHH   = OFF_FLAGS + 4096;
constexpr size_t OFF_WHL   = OFF_WHH + 64 * 40 * 64 * 8 / 2;
constexpr size_t OFF_WOH   = OFF_WHL + 64 * 40 * 64 * 8 / 2;
constexpr size_t OFF_WOL   = OFF_WOH + 64 * 32 * 64 * 8 / 2;

typedef __attribute__((ext_vector_type(8))) short short8v;
typedef __attribute__((ext_vector_type(4))) float f32x4;

static __device__ inline short f2bf(float f) {               // RTN-even fp32->bf16
    unsigned u = __builtin_bit_cast(unsigned, f);
    u += 0x7fffu + ((u >> 16) & 1u);
    return (short)(u >> 16);
}
static __device__ inline float bf2f(short s) {
    return __builtin_bit_cast(float, ((unsigned)(unsigned short)s) << 16);
}

__global__ __launch_bounds__(256)
void init_kernel(float* __restrict__ ws, const float* __restrict__ omega,
                 const float* __restrict__ b_offset, const float* __restrict__ tau_mem,
                 const float* __restrict__ gain) {
    size_t tid = (size_t)blockIdx.x * blockDim.x + threadIdx.x;
    size_t stride = (size_t)gridDim.x * blockDim.x;
    // zero hu buf0 (hi+lo contiguous) and flags — every call (graph replay safety)
    for (size_t i = tid; i < (size_t)B * H; i += stride) ws[OFF_HUH0 + i] = 0.0f;
    for (size_t i = tid; i < 4096; i += stride) ws[OFF_FLAGS + i] = 0.0f;
    if (tid < H) {
        float om  = fabsf(omega[tid]);
        float om2 = om * om;
        float bb  = om2 * 0.005f + fabsf(b_offset[tid]);
        float al  = expf(-1.0f / fabsf(tau_mem[tid]));
        float g   = gain[tid];
        ws[OFF_COEF + 0 * H + tid] = g * (1.0f - 2.0f * bb * DT);  // k1
        ws[OFF_COEF + 1 * H + tid] = g * DT;                       // k2
        ws[OFF_COEF + 2 * H + tid] = g * om2 * DT;                 // k3
        ws[OFF_COEF + 3 * H + tid] = al;                           // alpha
        ws[OFF_COEF + 4 * H + tid] = 1.0f - al;
    }
}

// W [N x Kd] fp32 -> bf16 hi/lo in MFMA B-fragment order (validated round 4).
template <int NKS, int KD>
__global__ __launch_bounds__(256)
void convert_kernel(const float* __restrict__ W, short* __restrict__ WH,
                    short* __restrict__ WL) {
    int g = blockIdx.x * 256 + threadIdx.x;
    int lane = g & 63;
    int ks = (g >> 6) % NKS;
    int cg = g / (NKS * 64);
    int col = cg * 16 + (lane & 15);
    int k = ks * 32 + ((lane >> 4) << 3);
    const float* src = W + (size_t)col * KD + k;
    short8v hi, lo;
    #pragma unroll
    for (int j = 0; j < 8; ++j) {
        float v = src[j];
        short h = f2bf(v);
        hi[j] = h;
        lo[j] = f2bf(v - bf2f(h));
    }
    *(short8v*)(WH + (size_t)g * 8) = hi;
    *(short8v*)(WL + (size_t)g * 8) = lo;
}

// Persistent RNN: 256 WGs (1/CU), 512 threads. WG = (colgrp 0..63, rowt 0..3),
// tile 32 rows x 16 cols. 4 independent row-group pipelines; group barrier =
// store-release own flag + 64-lane parallel poll of group's 64 flags.
// Per-tile state (hv, ou, osum, hu fp32) lives in registers.
__global__ __launch_bounds__(512)
void rnn_persist(const float* __restrict__ x, float* __restrict__ ws) {
    __shared__ float redS[4][32][18];
    __shared__ float redP[4][32][18];
    const float* coef = ws + OFF_COEF;
    float* osum_g = ws + OFF_OSUM;
    short* huhB[2] = {(short*)(ws + OFF_HUH0), (short*)(ws + OFF_HUH1)};
    short* hulB[2] = {(short*)(ws + OFF_HUL0), (short*)(ws + OFF_HUL1)};
    int* flags = (int*)(ws + OFF_FLAGS);
    const short8v* WHH = (const short8v*)(ws + OFF_WHH);
    const short8v* WHL = (const short8v*)(ws + OFF_WHL);
    const short8v* WOH = (const short8v*)(ws + OFF_WOH);
    const short8v* WOL = (const short8v*)(ws + OFF_WOL);

    const int wg = blockIdx.x;
    const int xcd = wg & 7, idx = wg >> 3;       // XCD-sharded colgrps (weights L2-local)
    const int colsub = idx & 7, rowt = idx >> 3;
    const int col0 = xcd * 128 + colsub * 16;
    const int row0 = rowt * 32;
    const int colgrp = xcd * 8 + colsub;

    const int tid = threadIdx.x;
    const int wid = tid >> 6, lane = tid & 63;
    const int mtile = wid & 1, ksl = wid >> 1;   // 2 mtiles x 4 kslices
    const int rowg = row0 + mtile * 16 + (lane & 15);
    const int koff = (lane >> 4) << 3;

    const short8v* BOH = WOH + (size_t)colgrp * NKS_O * 64 + lane;
    const short8v* BOL = WOL + (size_t)colgrp * NKS_O * 64 + lane;
    const short8v* BHH = WHH + (size_t)colgrp * NKS_H * 64 + lane;
    const short8v* BHL = WHL + (size_t)colgrp * NKS_H * 64 + lane;

    // epilogue ownership (step-invariant) + register-resident state
    const int er = tid >> 4, ec = tid & 15;
    const int gcol = col0 + ec;
    const size_t eix = (size_t)(row0 + er) * H + gcol;
    const float k1  = coef[gcol],         k2  = coef[H + gcol];
    const float k3  = coef[2 * H + gcol], al  = coef[3 * H + gcol];
    const float alm = coef[4 * H + gcol];
    float hv_r = 0.0f, ou_r = 0.0f, osum_r = 0.0f, huf_r = 0.0f;

    int* pollp  = flags + (rowt * 64 + (tid & 63)) * 16;
    int* myflag = flags + (rowt * 64 + colgrp) * 16;

    for (int s = 0; s <= T; ++s) {
        // wait: all same-rowt WGs finished iteration s-1 (wrote hu^s, read hu^{s-1})
        if (tid < 64) {
            while (__hip_atomic_load(pollp, __ATOMIC_ACQUIRE, __HIP_MEMORY_SCOPE_AGENT) < s) {}
        }
        __syncthreads();
        __threadfence();   // acquire: invalidate L1/L2-cached hu lines (r2-validated skeleton)

        const bool last = (s == T);
        const short* hh = huhB[s & 1] + (size_t)rowg * H + koff;
        const short* hl = hulB[s & 1] + (size_t)rowg * H + koff;
        f32x4 accS = {0, 0, 0, 0}, accP = {0, 0, 0, 0};

        #pragma unroll 2
        for (int ks = ksl * 8; ks < ksl * 8 + 8; ++ks) {
            short8v ah  = *(const short8v*)(hh + ks * 32);
            short8v alv = *(const short8v*)(hl + ks * 32);
            short8v bh = BOH[ks * 64];
            short8v bl = BOL[ks * 64];
            accP = __builtin_amdgcn_mfma_f32_16x16x32_bf16(ah, bh, accP, 0, 0, 0);
            accP = __builtin_amdgcn_mfma_f32_16x16x32_bf16(alv, bh, accP, 0, 0, 0);
            accP = __builtin_amdgcn_mfma_f32_16x16x32_bf16(ah, bl, accP, 0, 0, 0);
            if (!last) {
                short8v ch = BHH[(8 + ks) * 64];
                short8v cl = BHL[(8 + ks) * 64];
                accS = __builtin_amdgcn_mfma_f32_16x16x32_bf16(ah, ch, accS, 0, 0, 0);
                accS = __builtin_amdgcn_mfma_f32_16x16x32_bf16(alv, ch, accS, 0, 0, 0);
                accS = __builtin_amdgcn_mfma_f32_16x16x32_bf16(ah, cl, accS, 0, 0, 0);
            }
        }
        if (!last) {
            const float* xrow = x + (size_t)s * B * I + (size_t)rowg * I + koff;
            #pragma unroll
            for (int ks = ksl * 2; ks < ksl * 2 + 2; ++ks) {
                float4 a0 = *(const float4*)(xrow + ks * 32);
                float4 a1 = *(const float4*)(xrow + ks * 32 + 4);
                float av[8] = {a0.x, a0.y, a0.z, a0.w, a1.x, a1.y, a1.z, a1.w};
                short8v ah, alv;
                #pragma unroll
                for (int j = 0; j < 8; ++j) {
                    short h = f2bf(av[j]);
                    ah[j] = h;
                    alv[j] = f2bf(av[j] - bf2f(h));
                }
                short8v ch = BHH[ks * 64];
                short8v cl = BHL[ks * 64];
                accS = __builtin_amdgcn_mfma_f32_16x16x32_bf16(ah, ch, accS, 0, 0, 0);
                accS = __builtin_amdgcn_mfma_f32_16x16x32_bf16(alv, ch, accS, 0, 0, 0);
                accS = __builtin_amdgcn_mfma_f32_16x16x32_bf16(ah, cl, accS, 0, 0, 0);
            }
        }

        // C/D layout: col = lane&15, row = (lane>>4)*4 + r   [HW-verified]
        #pragma unroll
        for (int r = 0; r < 4; ++r) {
            int crow = mtile * 16 + ((lane >> 4) << 2) + r;
            redP[ksl][crow][lane & 15] = accP[r];
            redS[ksl][crow][lane & 15] = accS[r];
        }
        __syncthreads();

        {
            float p = (redP[0][er][ec] + redP[1][er][ec]) + (redP[2][er][ec] + redP[3][er][ec]);
            float oun = ou_r * al + p * alm;
            ou_r = oun;
            osum_r += oun;
            if (!last) {
                float si = (redS[0][er][ec] + redS[1][er][ec]) + (redS[2][er][ec] + redS[3][er][ec]);
                float hvn = hv_r + huf_r * DT;
                float hun = k1 * huf_r + k2 * si - k3 * hvn;
                hv_r = hvn;
                huf_r = hun;
                short h = f2bf(hun);
                huhB[(s + 1) & 1][eix] = h;
                hulB[(s + 1) & 1][eix] = f2bf(hun - bf2f(h));
            } else {
                osum_g[eix] = osum_r;
            }
        }
        __threadfence();     // release: drain/flush hu stores before flagging
        __syncthreads();
        if (tid == 0 && !last)
            __hip_atomic_store(myflag, s + 1, __ATOMIC_RELEASE, __HIP_MEMORY_SCOPE_AGENT);
    }
}

// out = osum @ W_out^T + T*b_out  (fp32 scalar, proven round 1)
__global__ __launch_bounds__(256)
void readout_kernel(const float* __restrict__ ou_sum, const float* __restrict__ W_out,
                    const float* __restrict__ b_out, float* __restrict__ out) {
    constexpr int KC = 128, BT = 32, CT = 16;
    __shared__ float act[BT][KC + 4];
    __shared__ float w[CT][KC + 4];
    int wg = blockIdx.x;
    int bt = wg & 3, cg = wg >> 2;
    int row0 = bt * BT, col0 = cg * CT;
    int tid = threadIdx.x;
    int c = tid & 15, rr = tid >> 4;

    float4 acc0 = {0, 0, 0, 0}, acc1 = {0, 0, 0, 0};
    for (int kc = 0; kc < H / KC; ++kc) {
        int k0 = kc * KC;
        for (int i = tid; i < BT * (KC / 4); i += 256) {
            int r = i >> 5, c4 = (i & 31) * 4;
            *(float4*)&act[r][c4] = *(const float4*)&ou_sum[(size_t)(row0 + r) * H + k0 + c4];
        }
        for (int i = tid; i < CT * (KC / 4); i += 256) {
            int r = i >> 5, c4 = (i & 31) * 4;
            *(float4*)&w[r][c4] = *(const float4*)&W_out[(size_t)(col0 + r) * H + k0 + c4];
        }
        __syncthreads();
        #pragma unroll
        for (int k4 = 0; k4 < KC / 4; ++k4) {
            float4 a0 = *(const float4*)&act[rr][k4 * 4];
            float4 a1 = *(const float4*)&act[rr + 16][k4 * 4];
            float4 w0 = *(const float4*)&w[c][k4 * 4];
            acc0.x = fmaf(a0.x, w0.x, acc0.x); acc0.y = fmaf(a0.y, w0.y, acc0.y);
            acc0.z = fmaf(a0.z, w0.z, acc0.z); acc0.w = fmaf(a0.w, w0.w, acc0.w);
            acc1.x = fmaf(a1.x, w0.x, acc1.x); acc1.y = fmaf(a1.y, w0.y, acc1.y);
            acc1.z = fmaf(a1.z, w0.z, acc1.z); acc1.w = fmaf(a1.w, w0.w, acc1.w);
        }
        __syncthreads();
    }
    float v0 = (acc0.x + acc0.y) + (acc0.z + acc0.w);
    float v1 = (acc1.x + acc1.y) + (acc1.z + acc1.w);
    int gcol = col0 + c;
    float bo = b_out[gcol] * (float)T;
    out[(size_t)(row0 + rr) * O + gcol] = v0 + bo;
    out[(size_t)(row0 + rr + 16) * O + gcol] = v1 + bo;
}

extern "C" void kernel_launch(void* const* d_in, const int* in_sizes, int n_in,
                              void* d_out, int out_size, void* d_ws, size_t ws_size,
                              hipStream_t stream) {
    const float* x        = (const float*)d_in[0];
    const float* W_h      = (const float*)d_in[1];
    const float* gain     = (const float*)d_in[2];
    const float* omega    = (const float*)d_in[3];
    const float* b_offset = (const float*)d_in[4];
    const float* W_o      = (const float*)d_in[5];
    const float* tau_mem  = (const float*)d_in[6];
    const float* W_out    = (const float*)d_in[7];
    const float* b_out    = (const float*)d_in[8];
    float* ws  = (float*)d_ws;
    float* out = (float*)d_out;

    init_kernel<<<512, 256, 0, stream>>>(ws, omega, b_offset, tau_mem, gain);
    convert_kernel<40, K><<<640, 256, 0, stream>>>(
        W_h, (short*)(ws + OFF_WHH), (short*)(ws + OFF_WHL));
    convert_kernel<32, H><<<512, 256, 0, stream>>>(
        W_o, (short*)(ws + OFF_WOH), (short*)(ws + OFF_WOL));

    rnn_persist<<<256, 512, 0, stream>>>(x, ws);

    readout_kernel<<<64, 256, 0, stream>>>(ws + OFF_OSUM, W_out, b_out, out);
}

// Round 6
// 6382.307 us; speedup vs baseline: 6.4541x; 6.4541x over previous
//
#include <hip/hip_runtime.h>
#include <math.h>

#define DT 0.01f
constexpr int T = 512, B = 128, I = 256, H = 1024, O = 256;
constexpr int K = I + H;          // 1280
constexpr int NKS_H = K / 32;     // 40 (W_h: ks 0..7 = x part, 8..39 = hu part)
constexpr int NKS_O = H / 32;     // 32 (W_o)

// ---- workspace layout (float offsets) ----
constexpr size_t OFF_OSUM  = 0;                              // B*H
constexpr size_t OFF_HUH0  = OFF_OSUM + (size_t)B * H;       // bf16 hi, B*H shorts
constexpr size_t OFF_HUL0  = OFF_HUH0 + (size_t)B * H / 2;
constexpr size_t OFF_HUH1  = OFF_HUL0 + (size_t)B * H / 2;
constexpr size_t OFF_HUL1  = OFF_HUH1 + (size_t)B * H / 2;
constexpr size_t OFF_COEF  = OFF_HUL1 + (size_t)B * H / 2;   // k1,k2,k3,al,1-al
constexpr size_t OFF_FLAGS = OFF_COEF + 5 * (size_t)H;       // 256 slots * 16 ints
constexpr size_t OFF_WHH   = OFF_FLAGS + 4096;
constexpr size_t OFF_WHL   = OFF_WHH + 64 * 40 * 64 * 8 / 2;
constexpr size_t OFF_WOH   = OFF_WHL + 64 * 40 * 64 * 8 / 2;
constexpr size_t OFF_WOL   = OFF_WOH + 64 * 32 * 64 * 8 / 2;

// ---- LDS layout (bytes): per-colgrp weight slices + reduction buffers ----
constexpr int SM_WOH  = 0;                 // 32 ks * 64 * 8 shorts = 32768 B
constexpr int SM_WHH  = 32768;             // 40 ks -> 40960 B
constexpr int SM_WHL  = 73728;             // 40960 B
constexpr int SM_RED  = 114688;            // redP [4][32][18] f32 = 9216 B
constexpr int SM_REDS = SM_RED + 9216;     // redS 9216 B
constexpr int SM_BYTES = SM_REDS + 9216;   // 133120 <= 163840

typedef __attribute__((ext_vector_type(8))) short short8v;
typedef __attribute__((ext_vector_type(4))) float f32x4;
typedef __attribute__((ext_vector_type(2))) unsigned long long ulong2v;

static __device__ inline short f2bf(float f) {               // RTN-even fp32->bf16
    unsigned u = __builtin_bit_cast(unsigned, f);
    u += 0x7fffu + ((u >> 16) & 1u);
    return (short)(u >> 16);
}
static __device__ inline float bf2f(short s) {
    return __builtin_bit_cast(float, ((unsigned)(unsigned short)s) << 16);
}

__global__ __launch_bounds__(256)
void init_kernel(float* __restrict__ ws, const float* __restrict__ omega,
                 const float* __restrict__ b_offset, const float* __restrict__ tau_mem,
                 const float* __restrict__ gain) {
    size_t tid = (size_t)blockIdx.x * blockDim.x + threadIdx.x;
    size_t stride = (size_t)gridDim.x * blockDim.x;
    // zero hu buf0 (hi+lo contiguous) and flags — every call (graph replay safety)
    for (size_t i = tid; i < (size_t)B * H; i += stride) ws[OFF_HUH0 + i] = 0.0f;
    for (size_t i = tid; i < 4096; i += stride) ws[OFF_FLAGS + i] = 0.0f;
    if (tid < H) {
        float om  = fabsf(omega[tid]);
        float om2 = om * om;
        float bb  = om2 * 0.005f + fabsf(b_offset[tid]);
        float al  = expf(-1.0f / fabsf(tau_mem[tid]));
        float g   = gain[tid];
        ws[OFF_COEF + 0 * H + tid] = g * (1.0f - 2.0f * bb * DT);  // k1
        ws[OFF_COEF + 1 * H + tid] = g * DT;                       // k2
        ws[OFF_COEF + 2 * H + tid] = g * om2 * DT;                 // k3
        ws[OFF_COEF + 3 * H + tid] = al;                           // alpha
        ws[OFF_COEF + 4 * H + tid] = 1.0f - al;
    }
}

// W [N x Kd] fp32 -> bf16 hi/lo in MFMA B-fragment order (validated round 4).
template <int NKS, int KD>
__global__ __launch_bounds__(256)
void convert_kernel(const float* __restrict__ W, short* __restrict__ WH,
                    short* __restrict__ WL) {
    int g = blockIdx.x * 256 + threadIdx.x;
    int lane = g & 63;
    int ks = (g >> 6) % NKS;
    int cg = g / (NKS * 64);
    int col = cg * 16 + (lane & 15);
    int k = ks * 32 + ((lane >> 4) << 3);
    const float* src = W + (size_t)col * KD + k;
    short8v hi, lo;
    #pragma unroll
    for (int j = 0; j < 8; ++j) {
        float v = src[j];
        short h = f2bf(v);
        hi[j] = h;
        lo[j] = f2bf(v - bf2f(h));
    }
    *(short8v*)(WH + (size_t)g * 8) = hi;
    *(short8v*)(WL + (size_t)g * 8) = lo;
}

// Persistent RNN v2: fence-free. hu exchanged via device-scope RELAXED atomics
// (write-through stores, cache-bypassing loads) -> no threadfence/wbl2 in loop.
// Weights (W_o hi, W_h hi/lo) LDS-resident; W_o lo L2-cached global.
// 256 WGs (1/CU via 133KB LDS) x 512 thr; WG=(colgrp,rowt), tile 32x16.
// 4 independent rowt pipelines; sync = relaxed flag store + 64-lane relaxed poll.
__global__ __launch_bounds__(512)
void rnn_persist(const float* __restrict__ x, float* __restrict__ ws) {
    extern __shared__ char sm[];
    const short8v* lWOH = (const short8v*)(sm + SM_WOH);
    const short8v* lWHH = (const short8v*)(sm + SM_WHH);
    const short8v* lWHL = (const short8v*)(sm + SM_WHL);
    float* redP = (float*)(sm + SM_RED);
    float* redS = (float*)(sm + SM_REDS);

    const float* coef = ws + OFF_COEF;
    float* osum_g = ws + OFF_OSUM;
    const short* huhS[2] = {(const short*)(ws + OFF_HUH0), (const short*)(ws + OFF_HUH1)};
    const short* hulS[2] = {(const short*)(ws + OFF_HUL0), (const short*)(ws + OFF_HUL1)};
    unsigned int* huhW[2] = {(unsigned int*)(ws + OFF_HUH0), (unsigned int*)(ws + OFF_HUH1)};
    unsigned int* hulW[2] = {(unsigned int*)(ws + OFF_HUL0), (unsigned int*)(ws + OFF_HUL1)};
    int* flags = (int*)(ws + OFF_FLAGS);

    const int wg = blockIdx.x;
    const int xcd = wg & 7, idx = wg >> 3;       // XCD-sharded colgrps
    const int colsub = idx & 7, rowt = idx >> 3;
    const int col0 = xcd * 128 + colsub * 16;
    const int row0 = rowt * 32;
    const int colgrp = xcd * 8 + colsub;

    const int tid = threadIdx.x;
    const int wid = tid >> 6, lane = tid & 63;
    const int mtile = wid & 1, ksl = wid >> 1;   // 2 mtiles x 4 kslices
    const int rowg = row0 + mtile * 16 + (lane & 15);
    const int koff = (lane >> 4) << 3;           // shorts

    // ---- stage this colgrp's weight slices into LDS (once) ----
    {
        const float4* srcO = (const float4*)(ws + OFF_WOH) + (size_t)colgrp * 2048;
        const float4* srcH = (const float4*)(ws + OFF_WHH) + (size_t)colgrp * 2560;
        const float4* srcL = (const float4*)(ws + OFF_WHL) + (size_t)colgrp * 2560;
        float4* dO = (float4*)(sm + SM_WOH);
        float4* dH = (float4*)(sm + SM_WHH);
        float4* dL = (float4*)(sm + SM_WHL);
        for (int i = tid; i < 2048; i += 512) dO[i] = srcO[i];
        for (int i = tid; i < 2560; i += 512) { dH[i] = srcH[i]; dL[i] = srcL[i]; }
    }

    const short8v* BOL = (const short8v*)(ws + OFF_WOL) + (size_t)colgrp * NKS_O * 64 + lane;

    // epilogue ownership (tid<256): row er, col pair (ec0, ec0+1)
    const int er = tid >> 3;
    const int ec0 = (tid & 7) * 2;
    const int gcol0 = col0 + ec0;
    const size_t erow = (size_t)(row0 + (er & 31));
    float k1a = 0, k1b = 0, k2a = 0, k2b = 0, k3a = 0, k3b = 0;
    float ala = 0, alb = 0, alma = 0, almb = 0;
    if (tid < 256) {
        k1a = coef[gcol0];         k1b = coef[gcol0 + 1];
        k2a = coef[H + gcol0];     k2b = coef[H + gcol0 + 1];
        k3a = coef[2 * H + gcol0]; k3b = coef[2 * H + gcol0 + 1];
        ala = coef[3 * H + gcol0]; alb = coef[3 * H + gcol0 + 1];
        alma = coef[4 * H + gcol0]; almb = coef[4 * H + gcol0 + 1];
    }
    float hva = 0, hvb = 0, oua = 0, oub = 0, osa = 0, osb = 0, hua = 0, hub = 0;

    int* pollp  = flags + ((rowt * 64 + (tid & 63)) << 4);
    int* myflag = flags + ((rowt * 64 + colgrp) << 4);

    for (int s = 0; s <= T; ++s) {
        // wait: all same-rowt WGs completed step s-1 (relaxed poll, no fences)
        if (tid < 64) {
            while (__hip_atomic_load(pollp, __ATOMIC_RELAXED, __HIP_MEMORY_SCOPE_AGENT) < s)
                __builtin_amdgcn_s_sleep(1);
        }
        __syncthreads();
        asm volatile("" ::: "memory");   // keep hu loads below the barrier

        const bool last = (s == T);
        const unsigned long long* hh64 =
            (const unsigned long long*)(huhS[s & 1]) + (((size_t)rowg * H + koff) >> 2);
        const unsigned long long* hl64 =
            (const unsigned long long*)(hulS[s & 1]) + (((size_t)rowg * H + koff) >> 2);
        f32x4 accS = {0, 0, 0, 0}, accP = {0, 0, 0, 0};

        #pragma unroll 2
        for (int ks = ksl * 8; ks < ksl * 8 + 8; ++ks) {
            unsigned long long a0 = __hip_atomic_load(hh64 + ks * 8,     __ATOMIC_RELAXED, __HIP_MEMORY_SCOPE_AGENT);
            unsigned long long a1 = __hip_atomic_load(hh64 + ks * 8 + 1, __ATOMIC_RELAXED, __HIP_MEMORY_SCOPE_AGENT);
            unsigned long long b0 = __hip_atomic_load(hl64 + ks * 8,     __ATOMIC_RELAXED, __HIP_MEMORY_SCOPE_AGENT);
            unsigned long long b1 = __hip_atomic_load(hl64 + ks * 8 + 1, __ATOMIC_RELAXED, __HIP_MEMORY_SCOPE_AGENT);
            short8v ah  = __builtin_bit_cast(short8v, (ulong2v){a0, a1});
            short8v alv = __builtin_bit_cast(short8v, (ulong2v){b0, b1});
            short8v bh = lWOH[ks * 64 + lane];
            short8v bl = BOL[ks * 64];
            accP = __builtin_amdgcn_mfma_f32_16x16x32_bf16(ah, bh, accP, 0, 0, 0);
            accP = __builtin_amdgcn_mfma_f32_16x16x32_bf16(alv, bh, accP, 0, 0, 0);
            accP = __builtin_amdgcn_mfma_f32_16x16x32_bf16(ah, bl, accP, 0, 0, 0);
            if (!last) {
                short8v ch = lWHH[(8 + ks) * 64 + lane];
                short8v cl = lWHL[(8 + ks) * 64 + lane];
                accS = __builtin_amdgcn_mfma_f32_16x16x32_bf16(ah, ch, accS, 0, 0, 0);
                accS = __builtin_amdgcn_mfma_f32_16x16x32_bf16(alv, ch, accS, 0, 0, 0);
                accS = __builtin_amdgcn_mfma_f32_16x16x32_bf16(ah, cl, accS, 0, 0, 0);
            }
        }
        if (!last) {
            const float* xrow = x + (size_t)s * B * I + (size_t)rowg * I + koff;
            #pragma unroll
            for (int ks = ksl * 2; ks < ksl * 2 + 2; ++ks) {
                float4 a0 = *(const float4*)(xrow + ks * 32);
                float4 a1 = *(const float4*)(xrow + ks * 32 + 4);
                float av[8] = {a0.x, a0.y, a0.z, a0.w, a1.x, a1.y, a1.z, a1.w};
                short8v ah, alv;
                #pragma unroll
                for (int j = 0; j < 8; ++j) {
                    short h = f2bf(av[j]);
                    ah[j] = h;
                    alv[j] = f2bf(av[j] - bf2f(h));
                }
                short8v ch = lWHH[ks * 64 + lane];
                short8v cl = lWHL[ks * 64 + lane];
                accS = __builtin_amdgcn_mfma_f32_16x16x32_bf16(ah, ch, accS, 0, 0, 0);
                accS = __builtin_amdgcn_mfma_f32_16x16x32_bf16(alv, ch, accS, 0, 0, 0);
                accS = __builtin_amdgcn_mfma_f32_16x16x32_bf16(ah, cl, accS, 0, 0, 0);
            }
        }

        // C/D layout: col = lane&15, row = (lane>>4)*4 + r   [HW-verified]
        #pragma unroll
        for (int r = 0; r < 4; ++r) {
            int crow = mtile * 16 + ((lane >> 4) << 2) + r;
            redP[ksl * 576 + crow * 18 + (lane & 15)] = accP[r];
            redS[ksl * 576 + crow * 18 + (lane & 15)] = accS[r];
        }
        __syncthreads();

        if (tid < 256) {
            int base = er * 18 + ec0;
            float p0 = (redP[base] + redP[576 + base]) + (redP[1152 + base] + redP[1728 + base]);
            float p1 = (redP[base + 1] + redP[576 + base + 1]) + (redP[1152 + base + 1] + redP[1728 + base + 1]);
            float o0 = oua * ala + p0 * alma; oua = o0; osa += o0;
            float o1 = oub * alb + p1 * almb; oub = o1; osb += o1;
            if (!last) {
                float s0 = (redS[base] + redS[576 + base]) + (redS[1152 + base] + redS[1728 + base]);
                float s1 = (redS[base + 1] + redS[576 + base + 1]) + (redS[1152 + base + 1] + redS[1728 + base + 1]);
                float hvn0 = hva + hua * DT;
                float hun0 = k1a * hua + k2a * s0 - k3a * hvn0;
                hva = hvn0; hua = hun0;
                float hvn1 = hvb + hub * DT;
                float hun1 = k1b * hub + k2b * s1 - k3b * hvn1;
                hvb = hvn1; hub = hun1;
                short h0 = f2bf(hun0), h1 = f2bf(hun1);
                short l0 = f2bf(hun0 - bf2f(h0)), l1 = f2bf(hun1 - bf2f(h1));
                unsigned hpack = (unsigned)(unsigned short)h0 | ((unsigned)(unsigned short)h1 << 16);
                unsigned lpack = (unsigned)(unsigned short)l0 | ((unsigned)(unsigned short)l1 << 16);
                size_t off32 = (erow * H + gcol0) >> 1;
                __hip_atomic_store(huhW[(s + 1) & 1] + off32, hpack, __ATOMIC_RELAXED, __HIP_MEMORY_SCOPE_AGENT);
                __hip_atomic_store(hulW[(s + 1) & 1] + off32, lpack, __ATOMIC_RELAXED, __HIP_MEMORY_SCOPE_AGENT);
            } else {
                osum_g[erow * H + gcol0] = osa;
                osum_g[erow * H + gcol0 + 1] = osb;
            }
        }
        asm volatile("s_waitcnt vmcnt(0)" ::: "memory");  // hu stores at coherence point
        __syncthreads();
        if (tid == 0 && !last)
            __hip_atomic_store(myflag, s + 1, __ATOMIC_RELAXED, __HIP_MEMORY_SCOPE_AGENT);
    }
}

// out = osum @ W_out^T + T*b_out  (fp32 scalar, proven round 1)
__global__ __launch_bounds__(256)
void readout_kernel(const float* __restrict__ ou_sum, const float* __restrict__ W_out,
                    const float* __restrict__ b_out, float* __restrict__ out) {
    constexpr int KC = 128, BT = 32, CT = 16;
    __shared__ float act[BT][KC + 4];
    __shared__ float w[CT][KC + 4];
    int wg = blockIdx.x;
    int bt = wg & 3, cg = wg >> 2;
    int row0 = bt * BT, col0 = cg * CT;
    int tid = threadIdx.x;
    int c = tid & 15, rr = tid >> 4;

    float4 acc0 = {0, 0, 0, 0}, acc1 = {0, 0, 0, 0};
    for (int kc = 0; kc < H / KC; ++kc) {
        int k0 = kc * KC;
        for (int i = tid; i < BT * (KC / 4); i += 256) {
            int r = i >> 5, c4 = (i & 31) * 4;
            *(float4*)&act[r][c4] = *(const float4*)&ou_sum[(size_t)(row0 + r) * H + k0 + c4];
        }
        for (int i = tid; i < CT * (KC / 4); i += 256) {
            int r = i >> 5, c4 = (i & 31) * 4;
            *(float4*)&w[r][c4] = *(const float4*)&W_out[(size_t)(col0 + r) * H + k0 + c4];
        }
        __syncthreads();
        #pragma unroll
        for (int k4 = 0; k4 < KC / 4; ++k4) {
            float4 a0 = *(const float4*)&act[rr][k4 * 4];
            float4 a1 = *(const float4*)&act[rr + 16][k4 * 4];
            float4 w0 = *(const float4*)&w[c][k4 * 4];
            acc0.x = fmaf(a0.x, w0.x, acc0.x); acc0.y = fmaf(a0.y, w0.y, acc0.y);
            acc0.z = fmaf(a0.z, w0.z, acc0.z); acc0.w = fmaf(a0.w, w0.w, acc0.w);
            acc1.x = fmaf(a1.x, w0.x, acc1.x); acc1.y = fmaf(a1.y, w0.y, acc1.y);
            acc1.z = fmaf(a1.z, w0.z, acc1.z); acc1.w = fmaf(a1.w, w0.w, acc1.w);
        }
        __syncthreads();
    }
    float v0 = (acc0.x + acc0.y) + (acc0.z + acc0.w);
    float v1 = (acc1.x + acc1.y) + (acc1.z + acc1.w);
    int gcol = col0 + c;
    float bo = b_out[gcol] * (float)T;
    out[(size_t)(row0 + rr) * O + gcol] = v0 + bo;
    out[(size_t)(row0 + rr + 16) * O + gcol] = v1 + bo;
}

extern "C" void kernel_launch(void* const* d_in, const int* in_sizes, int n_in,
                              void* d_out, int out_size, void* d_ws, size_t ws_size,
                              hipStream_t stream) {
    const float* x        = (const float*)d_in[0];
    const float* W_h      = (const float*)d_in[1];
    const float* gain     = (const float*)d_in[2];
    const float* omega    = (const float*)d_in[3];
    const float* b_offset = (const float*)d_in[4];
    const float* W_o      = (const float*)d_in[5];
    const float* tau_mem  = (const float*)d_in[6];
    const float* W_out    = (const float*)d_in[7];
    const float* b_out    = (const float*)d_in[8];
    float* ws  = (float*)d_ws;
    float* out = (float*)d_out;

    init_kernel<<<512, 256, 0, stream>>>(ws, omega, b_offset, tau_mem, gain);
    convert_kernel<40, K><<<640, 256, 0, stream>>>(
        W_h, (short*)(ws + OFF_WHH), (short*)(ws + OFF_WHL));
    convert_kernel<32, H><<<512, 256, 0, stream>>>(
        W_o, (short*)(ws + OFF_WOH), (short*)(ws + OFF_WOL));

    rnn_persist<<<256, 512, SM_BYTES, stream>>>(x, ws);

    readout_kernel<<<64, 256, 0, stream>>>(ws + OFF_OSUM, W_out, b_out, out);
}

// Round 7
// 3799.442 us; speedup vs baseline: 10.8416x; 1.6798x over previous
//
#include <hip/hip_runtime.h>
#include <math.h>

#define DT 0.01f
constexpr int T = 512, B = 128, I = 256, H = 1024, O = 256;
constexpr int K = I + H;          // 1280
constexpr int NKS_H = K / 32;     // 40 (W_h: ks 0..7 = x part, 8..39 = hu part)
constexpr int NKS_O = H / 32;     // 32 (W_o)

// ---- workspace layout (float offsets) ----
constexpr size_t OFF_OSUM  = 0;                              // B*H
constexpr size_t OFF_HUH0  = OFF_OSUM + (size_t)B * H;       // bf16 hi, B*H shorts
constexpr size_t OFF_HUL0  = OFF_HUH0 + (size_t)B * H / 2;
constexpr size_t OFF_HUH1  = OFF_HUL0 + (size_t)B * H / 2;
constexpr size_t OFF_HUL1  = OFF_HUH1 + (size_t)B * H / 2;
constexpr size_t OFF_COEF  = OFF_HUL1 + (size_t)B * H / 2;   // k1,k2,k3,al,1-al
constexpr size_t OFF_FLAGS = OFF_COEF + 5 * (size_t)H;       // 256 slots * 16 ints
constexpr size_t OFF_WHH   = OFF_FLAGS + 4096;
constexpr size_t OFF_WHL   = OFF_WHH + 64 * 40 * 64 * 8 / 2;
constexpr size_t OFF_WOH   = OFF_WHL + 64 * 40 * 64 * 8 / 2;
constexpr size_t OFF_WOL   = OFF_WOH + 64 * 32 * 64 * 8 / 2;

// ---- LDS layout (bytes): per-colgrp weight slices + reduction buffers ----
constexpr int SM_WOH  = 0;                 // 32 ks * 64 * 8 shorts = 32768 B
constexpr int SM_WHH  = 32768;             // 40 ks -> 40960 B
constexpr int SM_WHL  = 73728;             // 40960 B
constexpr int SM_RED  = 114688;            // redP [4][32][18] f32 = 9216 B
constexpr int SM_REDS = SM_RED + 9216;     // redS 9216 B
constexpr int SM_BYTES = SM_REDS + 9216;   // 133120 <= 163840

typedef __attribute__((ext_vector_type(8))) short short8v;
typedef __attribute__((ext_vector_type(4))) float f32x4;

static __device__ inline short f2bf(float f) {               // RTN-even fp32->bf16
    unsigned u = __builtin_bit_cast(unsigned, f);
    u += 0x7fffu + ((u >> 16) & 1u);
    return (short)(u >> 16);
}
static __device__ inline float bf2f(short s) {
    return __builtin_bit_cast(float, ((unsigned)(unsigned short)s) << 16);
}

__global__ __launch_bounds__(256)
void init_kernel(float* __restrict__ ws, const float* __restrict__ omega,
                 const float* __restrict__ b_offset, const float* __restrict__ tau_mem,
                 const float* __restrict__ gain) {
    size_t tid = (size_t)blockIdx.x * blockDim.x + threadIdx.x;
    size_t stride = (size_t)gridDim.x * blockDim.x;
    for (size_t i = tid; i < (size_t)B * H; i += stride) ws[OFF_HUH0 + i] = 0.0f;
    for (size_t i = tid; i < 4096; i += stride) ws[OFF_FLAGS + i] = 0.0f;
    if (tid < H) {
        float om  = fabsf(omega[tid]);
        float om2 = om * om;
        float bb  = om2 * 0.005f + fabsf(b_offset[tid]);
        float al  = expf(-1.0f / fabsf(tau_mem[tid]));
        float g   = gain[tid];
        ws[OFF_COEF + 0 * H + tid] = g * (1.0f - 2.0f * bb * DT);  // k1
        ws[OFF_COEF + 1 * H + tid] = g * DT;                       // k2
        ws[OFF_COEF + 2 * H + tid] = g * om2 * DT;                 // k3
        ws[OFF_COEF + 3 * H + tid] = al;                           // alpha
        ws[OFF_COEF + 4 * H + tid] = 1.0f - al;
    }
}

// W [N x Kd] fp32 -> bf16 hi/lo in MFMA B-fragment order (validated round 4).
template <int NKS, int KD>
__global__ __launch_bounds__(256)
void convert_kernel(const float* __restrict__ W, short* __restrict__ WH,
                    short* __restrict__ WL) {
    int g = blockIdx.x * 256 + threadIdx.x;
    int lane = g & 63;
    int ks = (g >> 6) % NKS;
    int cg = g / (NKS * 64);
    int col = cg * 16 + (lane & 15);
    int k = ks * 32 + ((lane >> 4) << 3);
    const float* src = W + (size_t)col * KD + k;
    short8v hi, lo;
    #pragma unroll
    for (int j = 0; j < 8; ++j) {
        float v = src[j];
        short h = f2bf(v);
        hi[j] = h;
        lo[j] = f2bf(v - bf2f(h));
    }
    *(short8v*)(WH + (size_t)g * 8) = hi;
    *(short8v*)(WL + (size_t)g * 8) = lo;
}

// Persistent RNN v3: hu exchange via 16B global_load_dwordx4 sc0 sc1 (L1/L2
// bypass, non-atomic streaming) with counted vmcnt batching; x-part GEMM and
// W_o-lo prefetch hoisted before the poll. Weights LDS-resident. 256 WGs x 512.
__global__ __launch_bounds__(512)
void rnn_persist(const float* __restrict__ x, float* __restrict__ ws) {
    extern __shared__ char sm[];
    const short8v* lWOH = (const short8v*)(sm + SM_WOH);
    const short8v* lWHH = (const short8v*)(sm + SM_WHH);
    const short8v* lWHL = (const short8v*)(sm + SM_WHL);
    float* redP = (float*)(sm + SM_RED);
    float* redS = (float*)(sm + SM_REDS);

    const float* coef = ws + OFF_COEF;
    float* osum_g = ws + OFF_OSUM;
    const short* huhS[2] = {(const short*)(ws + OFF_HUH0), (const short*)(ws + OFF_HUH1)};
    const short* hulS[2] = {(const short*)(ws + OFF_HUL0), (const short*)(ws + OFF_HUL1)};
    unsigned int* huhW[2] = {(unsigned int*)(ws + OFF_HUH0), (unsigned int*)(ws + OFF_HUH1)};
    unsigned int* hulW[2] = {(unsigned int*)(ws + OFF_HUL0), (unsigned int*)(ws + OFF_HUL1)};
    int* flags = (int*)(ws + OFF_FLAGS);

    const int wg = blockIdx.x;
    const int xcd = wg & 7, idx = wg >> 3;       // XCD-sharded colgrps
    const int colsub = idx & 7, rowt = idx >> 3;
    const int col0 = xcd * 128 + colsub * 16;
    const int row0 = rowt * 32;
    const int colgrp = xcd * 8 + colsub;

    const int tid = threadIdx.x;
    const int wid = tid >> 6, lane = tid & 63;
    const int mtile = wid & 1, ksl = wid >> 1;   // 2 mtiles x 4 kslices
    const int rowg = row0 + mtile * 16 + (lane & 15);
    const int koff = (lane >> 4) << 3;           // shorts

    // ---- stage this colgrp's weight slices into LDS (once) ----
    {
        const float4* srcO = (const float4*)(ws + OFF_WOH) + (size_t)colgrp * 2048;
        const float4* srcH = (const float4*)(ws + OFF_WHH) + (size_t)colgrp * 2560;
        const float4* srcL = (const float4*)(ws + OFF_WHL) + (size_t)colgrp * 2560;
        float4* dO = (float4*)(sm + SM_WOH);
        float4* dH = (float4*)(sm + SM_WHH);
        float4* dL = (float4*)(sm + SM_WHL);
        for (int i = tid; i < 2048; i += 512) dO[i] = srcO[i];
        for (int i = tid; i < 2560; i += 512) { dH[i] = srcH[i]; dL[i] = srcL[i]; }
    }

    const short8v* BOL = (const short8v*)(ws + OFF_WOL) + (size_t)colgrp * NKS_O * 64 + lane;

    // epilogue ownership (tid<256): row er, col pair (ec0, ec0+1)
    const int er = tid >> 3;
    const int ec0 = (tid & 7) * 2;
    const int gcol0 = col0 + ec0;
    const size_t erow = (size_t)(row0 + (er & 31));
    float k1a = 0, k1b = 0, k2a = 0, k2b = 0, k3a = 0, k3b = 0;
    float ala = 0, alb = 0, alma = 0, almb = 0;
    if (tid < 256) {
        k1a = coef[gcol0];         k1b = coef[gcol0 + 1];
        k2a = coef[H + gcol0];     k2b = coef[H + gcol0 + 1];
        k3a = coef[2 * H + gcol0]; k3b = coef[2 * H + gcol0 + 1];
        ala = coef[3 * H + gcol0]; alb = coef[3 * H + gcol0 + 1];
        alma = coef[4 * H + gcol0]; almb = coef[4 * H + gcol0 + 1];
    }
    float hva = 0, hvb = 0, oua = 0, oub = 0, osa = 0, osb = 0, hua = 0, hub = 0;

    int* pollp  = flags + ((rowt * 64 + (tid & 63)) << 4);
    int* myflag = flags + ((rowt * 64 + colgrp) << 4);

    for (int s = 0; s <= T; ++s) {
        const bool last = (s == T);
        f32x4 accS = {0, 0, 0, 0}, accP = {0, 0, 0, 0};

        // ---- pre-poll work: x-part GEMM (external input) + W_o-lo prefetch ----
        short8v bolbuf[8];
        #pragma unroll
        for (int j = 0; j < 8; ++j) bolbuf[j] = BOL[(ksl * 8 + j) * 64];
        if (!last) {
            const float* xrow = x + (size_t)s * B * I + (size_t)rowg * I + koff;
            #pragma unroll
            for (int ks = ksl * 2; ks < ksl * 2 + 2; ++ks) {
                float4 a0 = *(const float4*)(xrow + ks * 32);
                float4 a1 = *(const float4*)(xrow + ks * 32 + 4);
                float av[8] = {a0.x, a0.y, a0.z, a0.w, a1.x, a1.y, a1.z, a1.w};
                short8v ah, alv;
                #pragma unroll
                for (int j = 0; j < 8; ++j) {
                    short h = f2bf(av[j]);
                    ah[j] = h;
                    alv[j] = f2bf(av[j] - bf2f(h));
                }
                short8v ch = lWHH[ks * 64 + lane];
                short8v cl = lWHL[ks * 64 + lane];
                accS = __builtin_amdgcn_mfma_f32_16x16x32_bf16(ah, ch, accS, 0, 0, 0);
                accS = __builtin_amdgcn_mfma_f32_16x16x32_bf16(alv, ch, accS, 0, 0, 0);
                accS = __builtin_amdgcn_mfma_f32_16x16x32_bf16(ah, cl, accS, 0, 0, 0);
            }
        }

        // ---- wait: all same-rowt WGs completed step s-1 ----
        if (tid < 64) {
            while (__hip_atomic_load(pollp, __ATOMIC_RELAXED, __HIP_MEMORY_SCOPE_AGENT) < s)
                __builtin_amdgcn_s_sleep(1);
        }
        __syncthreads();
        asm volatile("" ::: "memory");   // keep hu loads below the barrier

        // ---- issue all 16 hu loads (16B, L1/L2-bypass streaming) ----
        const short* hbase = huhS[s & 1] + (size_t)rowg * H + koff;
        const short* lbase = hulS[s & 1] + (size_t)rowg * H + koff;
        short8v hbuf[8], lbuf[8];
        #pragma unroll
        for (int j = 0; j < 8; ++j) {
            const short* hp = hbase + (ksl * 8 + j) * 32;
            const short* lp = lbase + (ksl * 8 + j) * 32;
            asm volatile("global_load_dwordx4 %0, %1, off sc0 sc1"
                         : "=v"(hbuf[j]) : "v"(hp));
            asm volatile("global_load_dwordx4 %0, %1, off sc0 sc1"
                         : "=v"(lbuf[j]) : "v"(lp));
        }

        asm volatile("s_waitcnt vmcnt(8)");      // hbuf/lbuf[0..3] landed
        __builtin_amdgcn_sched_barrier(0);
        #pragma unroll
        for (int j = 0; j < 4; ++j) {
            int ks = ksl * 8 + j;
            short8v bh = lWOH[ks * 64 + lane];
            accP = __builtin_amdgcn_mfma_f32_16x16x32_bf16(hbuf[j], bh, accP, 0, 0, 0);
            accP = __builtin_amdgcn_mfma_f32_16x16x32_bf16(lbuf[j], bh, accP, 0, 0, 0);
            accP = __builtin_amdgcn_mfma_f32_16x16x32_bf16(hbuf[j], bolbuf[j], accP, 0, 0, 0);
            if (!last) {
                short8v ch = lWHH[(8 + ks) * 64 + lane];
                short8v cl = lWHL[(8 + ks) * 64 + lane];
                accS = __builtin_amdgcn_mfma_f32_16x16x32_bf16(hbuf[j], ch, accS, 0, 0, 0);
                accS = __builtin_amdgcn_mfma_f32_16x16x32_bf16(lbuf[j], ch, accS, 0, 0, 0);
                accS = __builtin_amdgcn_mfma_f32_16x16x32_bf16(hbuf[j], cl, accS, 0, 0, 0);
            }
        }
        asm volatile("s_waitcnt vmcnt(0)");      // rest landed
        __builtin_amdgcn_sched_barrier(0);
        #pragma unroll
        for (int j = 4; j < 8; ++j) {
            int ks = ksl * 8 + j;
            short8v bh = lWOH[ks * 64 + lane];
            accP = __builtin_amdgcn_mfma_f32_16x16x32_bf16(hbuf[j], bh, accP, 0, 0, 0);
            accP = __builtin_amdgcn_mfma_f32_16x16x32_bf16(lbuf[j], bh, accP, 0, 0, 0);
            accP = __builtin_amdgcn_mfma_f32_16x16x32_bf16(hbuf[j], bolbuf[j], accP, 0, 0, 0);
            if (!last) {
                short8v ch = lWHH[(8 + ks) * 64 + lane];
                short8v cl = lWHL[(8 + ks) * 64 + lane];
                accS = __builtin_amdgcn_mfma_f32_16x16x32_bf16(hbuf[j], ch, accS, 0, 0, 0);
                accS = __builtin_amdgcn_mfma_f32_16x16x32_bf16(lbuf[j], ch, accS, 0, 0, 0);
                accS = __builtin_amdgcn_mfma_f32_16x16x32_bf16(hbuf[j], cl, accS, 0, 0, 0);
            }
        }

        // C/D layout: col = lane&15, row = (lane>>4)*4 + r   [HW-verified]
        #pragma unroll
        for (int r = 0; r < 4; ++r) {
            int crow = mtile * 16 + ((lane >> 4) << 2) + r;
            redP[ksl * 576 + crow * 18 + (lane & 15)] = accP[r];
            redS[ksl * 576 + crow * 18 + (lane & 15)] = accS[r];
        }
        __syncthreads();

        if (tid < 256) {
            int base = er * 18 + ec0;
            float p0 = (redP[base] + redP[576 + base]) + (redP[1152 + base] + redP[1728 + base]);
            float p1 = (redP[base + 1] + redP[576 + base + 1]) + (redP[1152 + base + 1] + redP[1728 + base + 1]);
            float o0 = oua * ala + p0 * alma; oua = o0; osa += o0;
            float o1 = oub * alb + p1 * almb; oub = o1; osb += o1;
            if (!last) {
                float s0 = (redS[base] + redS[576 + base]) + (redS[1152 + base] + redS[1728 + base]);
                float s1 = (redS[base + 1] + redS[576 + base + 1]) + (redS[1152 + base + 1] + redS[1728 + base + 1]);
                float hvn0 = hva + hua * DT;
                float hun0 = k1a * hua + k2a * s0 - k3a * hvn0;
                hva = hvn0; hua = hun0;
                float hvn1 = hvb + hub * DT;
                float hun1 = k1b * hub + k2b * s1 - k3b * hvn1;
                hvb = hvn1; hub = hun1;
                short h0 = f2bf(hun0), h1 = f2bf(hun1);
                short l0 = f2bf(hun0 - bf2f(h0)), l1 = f2bf(hun1 - bf2f(h1));
                unsigned hpack = (unsigned)(unsigned short)h0 | ((unsigned)(unsigned short)h1 << 16);
                unsigned lpack = (unsigned)(unsigned short)l0 | ((unsigned)(unsigned short)l1 << 16);
                size_t off32 = (erow * H + gcol0) >> 1;
                __hip_atomic_store(huhW[(s + 1) & 1] + off32, hpack, __ATOMIC_RELAXED, __HIP_MEMORY_SCOPE_AGENT);
                __hip_atomic_store(hulW[(s + 1) & 1] + off32, lpack, __ATOMIC_RELAXED, __HIP_MEMORY_SCOPE_AGENT);
            } else {
                osum_g[erow * H + gcol0] = osa;
                osum_g[erow * H + gcol0 + 1] = osb;
            }
        }
        asm volatile("s_waitcnt vmcnt(0)" ::: "memory");  // hu stores at coherence point
        __syncthreads();
        if (tid == 0 && !last)
            __hip_atomic_store(myflag, s + 1, __ATOMIC_RELAXED, __HIP_MEMORY_SCOPE_AGENT);
    }
}

// out = osum @ W_out^T + T*b_out  (fp32 scalar, proven round 1)
__global__ __launch_bounds__(256)
void readout_kernel(const float* __restrict__ ou_sum, const float* __restrict__ W_out,
                    const float* __restrict__ b_out, float* __restrict__ out) {
    constexpr int KC = 128, BT = 32, CT = 16;
    __shared__ float act[BT][KC + 4];
    __shared__ float w[CT][KC + 4];
    int wg = blockIdx.x;
    int bt = wg & 3, cg = wg >> 2;
    int row0 = bt * BT, col0 = cg * CT;
    int tid = threadIdx.x;
    int c = tid & 15, rr = tid >> 4;

    float4 acc0 = {0, 0, 0, 0}, acc1 = {0, 0, 0, 0};
    for (int kc = 0; kc < H / KC; ++kc) {
        int k0 = kc * KC;
        for (int i = tid; i < BT * (KC / 4); i += 256) {
            int r = i >> 5, c4 = (i & 31) * 4;
            *(float4*)&act[r][c4] = *(const float4*)&ou_sum[(size_t)(row0 + r) * H + k0 + c4];
        }
        for (int i = tid; i < CT * (KC / 4); i += 256) {
            int r = i >> 5, c4 = (i & 31) * 4;
            *(float4*)&w[r][c4] = *(const float4*)&W_out[(size_t)(col0 + r) * H + k0 + c4];
        }
        __syncthreads();
        #pragma unroll
        for (int k4 = 0; k4 < KC / 4; ++k4) {
            float4 a0 = *(const float4*)&act[rr][k4 * 4];
            float4 a1 = *(const float4*)&act[rr + 16][k4 * 4];
            float4 w0 = *(const float4*)&w[c][k4 * 4];
            acc0.x = fmaf(a0.x, w0.x, acc0.x); acc0.y = fmaf(a0.y, w0.y, acc0.y);
            acc0.z = fmaf(a0.z, w0.z, acc0.z); acc0.w = fmaf(a0.w, w0.w, acc0.w);
            acc1.x = fmaf(a1.x, w0.x, acc1.x); acc1.y = fmaf(a1.y, w0.y, acc1.y);
            acc1.z = fmaf(a1.z, w0.z, acc1.z); acc1.w = fmaf(a1.w, w0.w, acc1.w);
        }
        __syncthreads();
    }
    float v0 = (acc0.x + acc0.y) + (acc0.z + acc0.w);
    float v1 = (acc1.x + acc1.y) + (acc1.z + acc1.w);
    int gcol = col0 + c;
    float bo = b_out[gcol] * (float)T;
    out[(size_t)(row0 + rr) * O + gcol] = v0 + bo;
    out[(size_t)(row0 + rr + 16) * O + gcol] = v1 + bo;
}

extern "C" void kernel_launch(void* const* d_in, const int* in_sizes, int n_in,
                              void* d_out, int out_size, void* d_ws, size_t ws_size,
                              hipStream_t stream) {
    const float* x        = (const float*)d_in[0];
    const float* W_h      = (const float*)d_in[1];
    const float* gain     = (const float*)d_in[2];
    const float* omega    = (const float*)d_in[3];
    const float* b_offset = (const float*)d_in[4];
    const float* W_o      = (const float*)d_in[5];
    const float* tau_mem  = (const float*)d_in[6];
    const float* W_out    = (const float*)d_in[7];
    const float* b_out    = (const float*)d_in[8];
    float* ws  = (float*)d_ws;
    float* out = (float*)d_out;

    init_kernel<<<512, 256, 0, stream>>>(ws, omega, b_offset, tau_mem, gain);
    convert_kernel<40, K><<<640, 256, 0, stream>>>(
        W_h, (short*)(ws + OFF_WHH), (short*)(ws + OFF_WHL));
    convert_kernel<32, H><<<512, 256, 0, stream>>>(
        W_o, (short*)(ws + OFF_WOH), (short*)(ws + OFF_WOL));

    rnn_persist<<<256, 512, SM_BYTES, stream>>>(x, ws);

    readout_kernel<<<64, 256, 0, stream>>>(ws + OFF_OSUM, W_out, b_out, out);
}